// Round 9
// baseline (214.229 us; speedup 1.0000x reference)
//
#include <hip/hip_runtime.h>

typedef short short8 __attribute__((ext_vector_type(8)));
typedef int   intx8  __attribute__((ext_vector_type(8)));
typedef float floatx16 __attribute__((ext_vector_type(16)));

typedef const __attribute__((address_space(1))) void* gas_t;
typedef __attribute__((address_space(3))) void* las_t;
__device__ __forceinline__ void gload16(const void* g, void* l) {
    __builtin_amdgcn_global_load_lds((gas_t)g, (las_t)l, 16, 0, 0);
}
__device__ __forceinline__ void gload4(const void* g, void* l) {
    __builtin_amdgcn_global_load_lds((gas_t)g, (las_t)l, 4, 0, 0);
}

__device__ __forceinline__ unsigned pk4(int a, int b, int c, int d) {
    return (a & 255) | ((b & 255) << 8) | ((c & 255) << 16) | ((unsigned)(d & 255) << 24);
}

// E4M3 code + E8M0 scale exponent (esf = sf-127) -> bf16 bits. Exact, integer-only.
// NaN code (e=15,m=7) decodes to 480*2^esf like the reference (fp8 can't use the
// HW f8f6f4 path: HW would produce NaN).
__device__ __forceinline__ unsigned dec8bf(int c, int esf) {
    int s = (c & 128) << 8;
    int e = (c >> 3) & 15, m = c & 7;
    int rn = s | ((e + 120 + esf) << 7) | (m << 4);                 // normal: (1+m/8)*2^(e-7)
    int nb = (m >= 4) ? 2 : ((m >= 2) ? 1 : 0);                     // floor(log2 m)
    int rs = m ? (s | ((nb + 118 + esf) << 7) | ((m << (7 - nb)) & 0x7F)) : s;  // subnormal m*2^-9
    return (unsigned)(e ? rn : rs);
}

// ---- prepass: LDS-staged repack, both global sides coalesced (r4-proven),
// single fused launch (r8-proven).
// C4 [96][R][16] : fp4 codes, chunk j = k nibbles 32j..32j+31
// C6 [24][R][24] : fp6 raw stream, window g = k 32g..32g+31
// C8 [32][R][8]  : fp8 decoded+scaled bf16, chunk j = k 8j..8j+7
// St [36][R][4]  : rows 0..23 fp4 scale quads; rows 24..35 fp6 scale pairs
__device__ __forceinline__ void pack_side_lds(
    int b, int t, unsigned* lds,
    const int* __restrict__ Pn, const int* __restrict__ Ps, const int* __restrict__ Po,
    const int* __restrict__ Sn, const int* __restrict__ Ss, const int* __restrict__ So,
    unsigned char* __restrict__ C4, unsigned char* __restrict__ C6,
    unsigned short* __restrict__ C8, unsigned char* __restrict__ St, int R)
{
    int per = R >> 6;
    if (b < 4 * per) {                             // ---- fp4: 64 rows x 24 chunks
        int jg = b / per, rb = b - jg * per, r0 = rb << 6;
        #pragma unroll
        for (int i = 0; i < 24; ++i) {
            int idx = i * 256 + t, row = idx / 96, q4 = idx - row * 96;
            int4 v = *(const int4*)(Pn + (size_t)(r0 + row) * 1536 + jg * 384 + q4 * 4);
            lds[row * 96 + q4] = pk4(v.x, v.y, v.z, v.w);
        }
        __syncthreads();
        #pragma unroll
        for (int i = 0; i < 6; ++i) {
            int idx = i * 256 + t, j = idx >> 6, row = idx & 63;
            uint4 v = *(uint4*)&lds[row * 96 + j * 4];
            *(uint4*)(C4 + ((size_t)(jg * 24 + j) * R + r0 + row) * 16) = v;
        }
    } else if (b < 5 * per) {                      // ---- fp6
        int rb = b - 4 * per, r0 = rb << 6;
        #pragma unroll
        for (int i = 0; i < 36; ++i) {
            int idx = i * 256 + t, row = idx / 144, q4 = idx - row * 144;
            int4 v = *(const int4*)(Ps + (size_t)(r0 + row) * 576 + q4 * 4);
            lds[row * 144 + q4] = pk4(v.x, v.y, v.z, v.w);
        }
        __syncthreads();
        #pragma unroll
        for (int i = 0; i < 18; ++i) {
            int idx = i * 256 + t, seg = idx / 192, off = idx - seg * 192;
            int row = off / 3, m3 = off - row * 3;
            int w0 = row * 144 + seg * 6 + m3 * 2;
            int2 v = { (int)lds[w0], (int)lds[w0 + 1] };
            *(int2*)(C6 + ((size_t)seg * R + r0) * 24 + (size_t)off * 8) = v;
        }
    } else if (b < 6 * per) {                      // ---- fp8: decode+scale to bf16
        int rb = b - 5 * per, r0 = rb << 6;
        #pragma unroll
        for (int i = 0; i < 16; ++i) {
            int idx = i * 256 + t, row = idx >> 6, q4 = idx & 63;
            int4 c = *(const int4*)(Po + (size_t)(r0 + row) * 256 + q4 * 4);
            int e = So[(size_t)(r0 + row) * 8 + (q4 >> 3)] - 127;
            lds[row * 128 + q4 * 2]     = dec8bf(c.x & 255, e) | (dec8bf(c.y & 255, e) << 16);
            lds[row * 128 + q4 * 2 + 1] = dec8bf(c.z & 255, e) | (dec8bf(c.w & 255, e) << 16);
        }
        __syncthreads();
        #pragma unroll
        for (int i = 0; i < 8; ++i) {
            int idx = i * 256 + t, seg = idx >> 6, row = idx & 63;
            uint4 v = *(uint4*)&lds[row * 128 + seg * 4];
            *(uint4*)((unsigned char*)C8 + ((size_t)seg * R + r0 + row) * 16) = v;
        }
    } else if (b < 7 * per) {                      // ---- fp4 scale quads
        int rb = b - 6 * per, r0 = rb << 6;
        #pragma unroll
        for (int i = 0; i < 6; ++i) {
            int idx = i * 256 + t, row = idx / 24, q4 = idx - row * 24;
            int4 v = *(const int4*)(Sn + (size_t)(r0 + row) * 96 + q4 * 4);
            lds[row * 24 + q4] = pk4(v.x, v.y, v.z, v.w);
        }
        __syncthreads();
        #pragma unroll
        for (int i = 0; i < 6; ++i) {
            int idx = i * 256 + t, seg = idx >> 6, row = idx & 63;
            *(unsigned*)(St + ((size_t)seg * R + r0 + row) * 4) = lds[row * 24 + seg];
        }
    } else {                                       // ---- fp6 scale pairs
        int rb = b - 7 * per, r0 = rb << 6;
        #pragma unroll
        for (int i = 0; i < 3; ++i) {
            int idx = i * 256 + t, row = idx / 12, b2 = idx - row * 12;
            int2 v = *(const int2*)(Ss + (size_t)(r0 + row) * 24 + b2 * 2);
            lds[row * 12 + b2] = (unsigned)((v.x & 255) | ((v.y & 255) << 8));
        }
        __syncthreads();
        #pragma unroll
        for (int i = 0; i < 3; ++i) {
            int idx = i * 256 + t, seg = idx >> 6, row = idx & 63;
            *(unsigned*)(St + ((size_t)(24 + seg) * R + r0 + row) * 4) = lds[row * 12 + seg];
        }
    }
}

__global__ __launch_bounds__(256) void pack_all(
    const int* __restrict__ AN, const int* __restrict__ AS, const int* __restrict__ AO,
    const int* __restrict__ SAn, const int* __restrict__ SAs, const int* __restrict__ SAo,
    unsigned char* __restrict__ A4, unsigned char* __restrict__ A6,
    unsigned short* __restrict__ A8, unsigned char* __restrict__ SaT, int M,
    const int* __restrict__ BN, const int* __restrict__ BS, const int* __restrict__ BO,
    const int* __restrict__ SBn, const int* __restrict__ SBs, const int* __restrict__ SBo,
    unsigned char* __restrict__ B4, unsigned char* __restrict__ B6,
    unsigned short* __restrict__ B8, unsigned char* __restrict__ SbT, int N)
{
    __shared__ unsigned lds[9216];                 // 36 KB, max section (fp6)
    int b = blockIdx.x, t = threadIdx.x;
    int nA = (M >> 6) * 8;
    if (b < nA) pack_side_lds(b, t, lds, AN, AS, AO, SAn, SAs, SAo, A4, A6, A8, SaT, M);
    else        pack_side_lds(b - nA, t, lds, BN, BS, BO, SBn, SBs, SBo, B4, B6, B8, SbT, N);
}

// ---- MX GEMM v9: fp4 section LDS-staged with CORRECTED counted-vmcnt pipeline.
// 128x128 block, 4 waves, 2x2 of 32x32 acc/wave, (256,3) = 3 blocks/CU (r5
// proved this config spill-free at 76 VGPR once frags live in LDS).
// r5's regression was an accounting bug: odd-step vmcnt(4) forced stage(u+1)
// (issued 1 step earlier) to complete -> effective lead 1 step. v9 fixes:
//  - lead-3 (4 frag bufs, stage u+3), ~1200cy cover
//  - ALL loop VMEM is global_load_lds (scales staged to LDS too) -> the vmcnt
//    queue is exactly enumerable; loads newer than stage(u) = 5 (u even) /
//    6 (u odd), hand-verified for steady state AND prologue steps 0..4; these
//    waits also cover the consumed scale buffer with >=2 items of slack.
//  - step order {vmcnt; barrier; ds_read; stage-issue; setprio+4xMFMA}: WAR-
//    safe (stage(u+3) overwrites buf(u-1); its readers' lgkmcnt(0) precedes
//    their barrier(u) arrival, and our stage issue follows barrier(u)).
// fp6/fp8: exact r1 register pipelines (issue-early/setprio reverted -- r8
// measured +8pt VALUBusy, -3us). Tail stages are bounded stray reads into the
// adjacent ws region (values never consumed).
__global__ __launch_bounds__(256, 3) void gemm_mx(
    const unsigned char* __restrict__ A4, const unsigned char* __restrict__ B4,
    const unsigned char* __restrict__ A6, const unsigned char* __restrict__ B6,
    const unsigned short* __restrict__ A8, const unsigned short* __restrict__ B8,
    const unsigned char* __restrict__ SaT, const unsigned char* __restrict__ SbT,
    const float* __restrict__ bias, float* __restrict__ C, int M, int N)
{
    __shared__ int4 ldsm[2304];                    // 36 KB = 4 frag bufs x 8KB + 4 scale bufs x 1KB
    char* ldsb = (char*)ldsm;
    char* scbb = ldsb + 32768;
    int tid = threadIdx.x, w = tid >> 6, l = tid & 63;
    int bm = blockIdx.y, bn = blockIdx.x;
    int wm = (w >> 1) * 64, wn = (w & 1) * 64;
    int lr = l & 31, lh = l >> 5;

    floatx16 acc[2][2] = {};

    int rA[2] = { bm * 128 + wm + lr, bm * 128 + wm + 32 + lr };
    int cB[2] = { bn * 128 + wn + lr, bn * 128 + wn + 32 + lr };

    // ================= fp4 (fmt 4): 48 steps of K=64, LDS lead-3 pipeline =================
    {
        unsigned strA = 32u * (unsigned)M, strB = 32u * (unsigned)N;
        // frag stage: wave w provides chunk (2v + (w>>1)), rows bm*128+(w&1)*64+l
        // -> buf layout [chunk(lh)][128 rows][16B] A at 0, B at +4096 (r5-verified).
        unsigned gA = ((unsigned)(w >> 1) * (unsigned)M + (unsigned)(bm * 128 + (w & 1) * 64 + l)) * 16u;
        unsigned gB = ((unsigned)(w >> 1) * (unsigned)N + (unsigned)(bn * 128 + (w & 1) * 64 + l)) * 16u;
        // scale stage: waves 0,1 -> SaT rows; waves 2,3 -> SbT rows. 1 dword/lane.
        // scale buf layout: [A 128 words][B 128 words] = 1KB per q-buf.
        const unsigned char* Sbase = (w < 2) ? SaT : SbT;
        unsigned sstr = 4u * (unsigned)((w < 2) ? M : N);
        unsigned gS = (unsigned)(((w < 2) ? bm : bn) * 128 + (w & 1) * 64 + l) * 4u;
        char* lw = ldsb + w * 1024;                // frag dest within a buf
        char* sw = scbb + w * 256;                 // scale dest within a scale buf

        // prologue queue (exactly 8 loads/wave): f0,f0,s0,f1,f1,s1,f2,f2
        gload16(A4 + gA, lw);                    gload16(B4 + gB, lw + 4096);
        gload4(Sbase + gS, sw);
        gload16(A4 + gA + strA, lw + 8192);      gload16(B4 + gB + strB, lw + 8192 + 4096);
        gload4(Sbase + gS + sstr, sw + 1024);
        gload16(A4 + gA + 2 * strA, lw + 16384); gload16(B4 + gB + 2 * strB, lw + 16384 + 4096);
        gA += 3 * strA; gB += 3 * strB; gS += 2 * sstr;   // next: frag v=3, scale q=2

        const int aof = ((wm + lr) << 4);          // + lh*2048 chunk select
        const int bof = 4096 + ((wn + lr) << 4);
        const int sao = (wm + lr) * 4;             // scale word offsets
        const int sbo = 512 + (wn + lr) * 4;

#define FP4_STEP(U)                                                                     \
        {                                                                               \
            asm volatile("s_waitcnt vmcnt(%0)" :: "i"(((U) & 1) ? 6 : 5) : "memory");   \
            __builtin_amdgcn_s_barrier();                                               \
            const char* fb = ldsb + ((U) & 3) * 8192 + (lh << 11);                      \
            int4 va0 = *(const int4*)(fb + aof), va1 = *(const int4*)(fb + aof + 512);  \
            int4 vb0 = *(const int4*)(fb + bof), vb1 = *(const int4*)(fb + bof + 512);  \
            const char* sb = scbb + (((U) >> 1) & 3) * 1024;                            \
            unsigned wa0 = *(const unsigned*)(sb + sao);                                \
            unsigned wa1 = *(const unsigned*)(sb + sao + 128);                          \
            unsigned wb0 = *(const unsigned*)(sb + sbo);                                \
            unsigned wb1 = *(const unsigned*)(sb + sbo + 128);                          \
            gload16(A4 + gA, ldsb + (((U) + 3) & 3) * 8192 + w * 1024);                 \
            gload16(B4 + gB, ldsb + (((U) + 3) & 3) * 8192 + 4096 + w * 1024);          \
            gA += strA; gB += strB;                                                     \
            if (!((U) & 1)) {                                                           \
                gload4(Sbase + gS, scbb + ((((U) >> 1) + 2) & 3) * 1024 + w * 256);     \
                gS += sstr;                                                             \
            }                                                                           \
            int sh = 8 * (((U) & 1) * 2 + lh);                                          \
            int sa0 = (int)((wa0 >> sh) & 255), sa1 = (int)((wa1 >> sh) & 255);         \
            int sb0_ = (int)((wb0 >> sh) & 255), sb1_ = (int)((wb1 >> sh) & 255);       \
            intx8 A0 = (intx8){ va0.x, va0.y, va0.z, va0.w, 0, 0, 0, 0 };               \
            intx8 A1 = (intx8){ va1.x, va1.y, va1.z, va1.w, 0, 0, 0, 0 };               \
            intx8 B0 = (intx8){ vb0.x, vb0.y, vb0.z, vb0.w, 0, 0, 0, 0 };               \
            intx8 B1 = (intx8){ vb1.x, vb1.y, vb1.z, vb1.w, 0, 0, 0, 0 };               \
            __builtin_amdgcn_s_setprio(1);                                              \
            acc[0][0] = __builtin_amdgcn_mfma_scale_f32_32x32x64_f8f6f4(A0, B0, acc[0][0], 4, 4, 0, sa0, 0, sb0_); \
            acc[0][1] = __builtin_amdgcn_mfma_scale_f32_32x32x64_f8f6f4(A0, B1, acc[0][1], 4, 4, 0, sa0, 0, sb1_); \
            acc[1][0] = __builtin_amdgcn_mfma_scale_f32_32x32x64_f8f6f4(A1, B0, acc[1][0], 4, 4, 0, sa1, 0, sb0_); \
            acc[1][1] = __builtin_amdgcn_mfma_scale_f32_32x32x64_f8f6f4(A1, B1, acc[1][1], 4, 4, 0, sa1, 0, sb1_); \
            __builtin_amdgcn_s_setprio(0);                                              \
        }

        for (int it = 0; it < 6; ++it) {           // 48 steps; all mod-8 indices static
            FP4_STEP(0) FP4_STEP(1) FP4_STEP(2) FP4_STEP(3)
            FP4_STEP(4) FP4_STEP(5) FP4_STEP(6) FP4_STEP(7)
        }
#undef FP4_STEP
    }

    // ================= fp6 (fmt 3): 12 steps of K=64, depth-2 register pipeline =================
    {
        unsigned str6A = 48u * (unsigned)M, str6B = 48u * (unsigned)N;
        unsigned gA0 = ((unsigned)lh * M + (unsigned)rA[0]) * 24u;
        unsigned gA1 = ((unsigned)lh * M + (unsigned)rA[1]) * 24u;
        unsigned gB0 = ((unsigned)lh * N + (unsigned)cB[0]) * 24u;
        unsigned gB1 = ((unsigned)lh * N + (unsigned)cB[1]) * 24u;
        unsigned ss4A = 4u * (unsigned)M, ss4B = 4u * (unsigned)N;
        unsigned zA0 = (24u * (unsigned)M + (unsigned)rA[0]) * 4u;
        unsigned zA1 = (24u * (unsigned)M + (unsigned)rA[1]) * 4u;
        unsigned zB0 = (24u * (unsigned)N + (unsigned)cB[0]) * 4u;
        unsigned zB1 = (24u * (unsigned)N + (unsigned)cB[1]) * 4u;

        int2 qa[2][2][3], qb[2][2][3];
        unsigned p6a[2][2], p6b[2][2];
        #pragma unroll
        for (int s = 0; s < 2; ++s) {
            const unsigned char *a0 = A6 + gA0, *a1 = A6 + gA1, *b0 = B6 + gB0, *b1 = B6 + gB1;
            qa[s][0][0] = *(const int2*)(a0); qa[s][0][1] = *(const int2*)(a0 + 8); qa[s][0][2] = *(const int2*)(a0 + 16);
            qa[s][1][0] = *(const int2*)(a1); qa[s][1][1] = *(const int2*)(a1 + 8); qa[s][1][2] = *(const int2*)(a1 + 16);
            qb[s][0][0] = *(const int2*)(b0); qb[s][0][1] = *(const int2*)(b0 + 8); qb[s][0][2] = *(const int2*)(b0 + 16);
            qb[s][1][0] = *(const int2*)(b1); qb[s][1][1] = *(const int2*)(b1 + 8); qb[s][1][2] = *(const int2*)(b1 + 16);
            p6a[s][0] = *(const unsigned*)(SaT + zA0); p6a[s][1] = *(const unsigned*)(SaT + zA1);
            p6b[s][0] = *(const unsigned*)(SbT + zB0); p6b[s][1] = *(const unsigned*)(SbT + zB1);
            gA0 += str6A; gA1 += str6A; gB0 += str6B; gB1 += str6B;
            zA0 += ss4A; zA1 += ss4A; zB0 += ss4B; zB1 += ss4B;
        }
        int sh6 = 8 * lh;
        #pragma unroll 2
        for (int v = 0; v < 10; ++v) {
            int sl = v & 1;
            int sa0 = (int)((p6a[sl][0] >> sh6) & 255), sa1 = (int)((p6a[sl][1] >> sh6) & 255);
            int sb0 = (int)((p6b[sl][0] >> sh6) & 255), sb1 = (int)((p6b[sl][1] >> sh6) & 255);
            intx8 A0 = (intx8){ qa[sl][0][0].x, qa[sl][0][0].y, qa[sl][0][1].x, qa[sl][0][1].y, qa[sl][0][2].x, qa[sl][0][2].y, 0, 0 };
            intx8 A1 = (intx8){ qa[sl][1][0].x, qa[sl][1][0].y, qa[sl][1][1].x, qa[sl][1][1].y, qa[sl][1][2].x, qa[sl][1][2].y, 0, 0 };
            intx8 B0 = (intx8){ qb[sl][0][0].x, qb[sl][0][0].y, qb[sl][0][1].x, qb[sl][0][1].y, qb[sl][0][2].x, qb[sl][0][2].y, 0, 0 };
            intx8 B1 = (intx8){ qb[sl][1][0].x, qb[sl][1][0].y, qb[sl][1][1].x, qb[sl][1][1].y, qb[sl][1][2].x, qb[sl][1][2].y, 0, 0 };
            acc[0][0] = __builtin_amdgcn_mfma_scale_f32_32x32x64_f8f6f4(A0, B0, acc[0][0], 3, 3, 0, sa0, 0, sb0);
            acc[0][1] = __builtin_amdgcn_mfma_scale_f32_32x32x64_f8f6f4(A0, B1, acc[0][1], 3, 3, 0, sa0, 0, sb1);
            acc[1][0] = __builtin_amdgcn_mfma_scale_f32_32x32x64_f8f6f4(A1, B0, acc[1][0], 3, 3, 0, sa1, 0, sb0);
            acc[1][1] = __builtin_amdgcn_mfma_scale_f32_32x32x64_f8f6f4(A1, B1, acc[1][1], 3, 3, 0, sa1, 0, sb1);
            {   // prefetch v+2 into slot just consumed (v+2 <= 11: fully in-bounds)
                const unsigned char *a0 = A6 + gA0, *a1 = A6 + gA1, *b0 = B6 + gB0, *b1 = B6 + gB1;
                qa[sl][0][0] = *(const int2*)(a0); qa[sl][0][1] = *(const int2*)(a0 + 8); qa[sl][0][2] = *(const int2*)(a0 + 16);
                qa[sl][1][0] = *(const int2*)(a1); qa[sl][1][1] = *(const int2*)(a1 + 8); qa[sl][1][2] = *(const int2*)(a1 + 16);
                qb[sl][0][0] = *(const int2*)(b0); qb[sl][0][1] = *(const int2*)(b0 + 8); qb[sl][0][2] = *(const int2*)(b0 + 16);
                qb[sl][1][0] = *(const int2*)(b1); qb[sl][1][1] = *(const int2*)(b1 + 8); qb[sl][1][2] = *(const int2*)(b1 + 16);
                p6a[sl][0] = *(const unsigned*)(SaT + zA0); p6a[sl][1] = *(const unsigned*)(SaT + zA1);
                p6b[sl][0] = *(const unsigned*)(SbT + zB0); p6b[sl][1] = *(const unsigned*)(SbT + zB1);
                gA0 += str6A; gA1 += str6A; gB0 += str6B; gB1 += str6B;
                zA0 += ss4A; zA1 += ss4A; zB0 += ss4B; zB1 += ss4B;
            }
        }
        #pragma unroll
        for (int v = 10; v < 12; ++v) {   // peeled tail: consume-only (no stray scale reads)
            int sl = v & 1;
            int sa0 = (int)((p6a[sl][0] >> sh6) & 255), sa1 = (int)((p6a[sl][1] >> sh6) & 255);
            int sb0 = (int)((p6b[sl][0] >> sh6) & 255), sb1 = (int)((p6b[sl][1] >> sh6) & 255);
            intx8 A0 = (intx8){ qa[sl][0][0].x, qa[sl][0][0].y, qa[sl][0][1].x, qa[sl][0][1].y, qa[sl][0][2].x, qa[sl][0][2].y, 0, 0 };
            intx8 A1 = (intx8){ qa[sl][1][0].x, qa[sl][1][0].y, qa[sl][1][1].x, qa[sl][1][1].y, qa[sl][1][2].x, qa[sl][1][2].y, 0, 0 };
            intx8 B0 = (intx8){ qb[sl][0][0].x, qb[sl][0][0].y, qb[sl][0][1].x, qb[sl][0][1].y, qb[sl][0][2].x, qb[sl][0][2].y, 0, 0 };
            intx8 B1 = (intx8){ qb[sl][1][0].x, qb[sl][1][0].y, qb[sl][1][1].x, qb[sl][1][1].y, qb[sl][1][2].x, qb[sl][1][2].y, 0, 0 };
            acc[0][0] = __builtin_amdgcn_mfma_scale_f32_32x32x64_f8f6f4(A0, B0, acc[0][0], 3, 3, 0, sa0, 0, sb0);
            acc[0][1] = __builtin_amdgcn_mfma_scale_f32_32x32x64_f8f6f4(A0, B1, acc[0][1], 3, 3, 0, sa0, 0, sb1);
            acc[1][0] = __builtin_amdgcn_mfma_scale_f32_32x32x64_f8f6f4(A1, B0, acc[1][0], 3, 3, 0, sa1, 0, sb0);
            acc[1][1] = __builtin_amdgcn_mfma_scale_f32_32x32x64_f8f6f4(A1, B1, acc[1][1], 3, 3, 0, sa1, 0, sb1);
        }
    }

    // ================= fp8 as bf16: 16 steps of K=16, depth-2 register pipeline =================
    {
        unsigned str8A = 32u * (unsigned)M, str8B = 32u * (unsigned)N;
        const unsigned char* A8b = (const unsigned char*)A8;
        const unsigned char* B8b = (const unsigned char*)B8;
        unsigned hA0 = ((unsigned)lh * M + (unsigned)rA[0]) * 16u;
        unsigned hA1 = ((unsigned)lh * M + (unsigned)rA[1]) * 16u;
        unsigned hB0 = ((unsigned)lh * N + (unsigned)cB[0]) * 16u;
        unsigned hB1 = ((unsigned)lh * N + (unsigned)cB[1]) * 16u;
        short8 ra[2][2], rb[2][2];
        #pragma unroll
        for (int s = 0; s < 2; ++s) {
            ra[s][0] = *(const short8*)(A8b + hA0); ra[s][1] = *(const short8*)(A8b + hA1);
            rb[s][0] = *(const short8*)(B8b + hB0); rb[s][1] = *(const short8*)(B8b + hB1);
            hA0 += str8A; hA1 += str8A; hB0 += str8B; hB1 += str8B;
        }
        #pragma unroll 2
        for (int q = 0; q < 16; ++q) {
            int sl = q & 1;
            acc[0][0] = __builtin_amdgcn_mfma_f32_32x32x16_bf16(ra[sl][0], rb[sl][0], acc[0][0], 0, 0, 0);
            acc[0][1] = __builtin_amdgcn_mfma_f32_32x32x16_bf16(ra[sl][0], rb[sl][1], acc[0][1], 0, 0, 0);
            acc[1][0] = __builtin_amdgcn_mfma_f32_32x32x16_bf16(ra[sl][1], rb[sl][0], acc[1][0], 0, 0, 0);
            acc[1][1] = __builtin_amdgcn_mfma_f32_32x32x16_bf16(ra[sl][1], rb[sl][1], acc[1][1], 0, 0, 0);
            // prefetch q+2 (tail strays stay inside A8->B8 / B8->SaT regions)
            ra[sl][0] = *(const short8*)(A8b + hA0); ra[sl][1] = *(const short8*)(A8b + hA1);
            rb[sl][0] = *(const short8*)(B8b + hB0); rb[sl][1] = *(const short8*)(B8b + hB1);
            hA0 += str8A; hA1 += str8A; hB0 += str8B; hB1 += str8B;
        }
    }

    // epilogue: 32x32 C/D layout col=lane&31, row=(r&3)+8*(r>>2)+4*lh (m74/m101-verified)
    #pragma unroll
    for (int i = 0; i < 2; i++)
        #pragma unroll
        for (int j = 0; j < 2; j++) {
            int col = bn * 128 + wn + j * 32 + lr;
            float bv = bias[col];
            #pragma unroll
            for (int r = 0; r < 16; r++) {
                int row = bm * 128 + wm + i * 32 + (r & 3) + 8 * (r >> 2) + 4 * lh;
                C[(size_t)row * N + col] = acc[i][j][r] + bv;
            }
        }
}

extern "C" void kernel_launch(void* const* d_in, const int* in_sizes, int n_in,
                              void* d_out, int out_size, void* d_ws, size_t ws_size,
                              hipStream_t stream) {
    const int* AN   = (const int*)d_in[0];
    const int* ASs  = (const int*)d_in[1];
    const int* AO   = (const int*)d_in[2];
    const int* SFAN = (const int*)d_in[3];
    const int* SFAS = (const int*)d_in[4];
    const int* SFAO = (const int*)d_in[5];
    const int* BN   = (const int*)d_in[6];
    const int* BS   = (const int*)d_in[7];
    const int* BO   = (const int*)d_in[8];
    const int* SFBN = (const int*)d_in[9];
    const int* SFBS = (const int*)d_in[10];
    const int* SFBO = (const int*)d_in[11];
    const float* bias = (const float*)d_in[12];

    int M = in_sizes[0] / 1536;
    int N = in_sizes[6] / 1536;

    unsigned char* ws = (unsigned char*)d_ws;
    size_t o = 0;
    unsigned char*  A4c = ws + o;                    o += (size_t)M * 1536;
    unsigned char*  B4c = ws + o;                    o += (size_t)N * 1536;
    unsigned char*  A6c = ws + o;                    o += (size_t)M * 576;
    unsigned char*  B6c = ws + o;                    o += (size_t)N * 576;
    unsigned short* A8d = (unsigned short*)(ws + o); o += (size_t)M * 512;
    unsigned short* B8d = (unsigned short*)(ws + o); o += (size_t)N * 512;
    unsigned char*  SaT = ws + o;                    o += (size_t)36 * M * 4;
    unsigned char*  SbT = ws + o;                    o += (size_t)36 * N * 4;

    int nblk = (M >> 6) * 8 + (N >> 6) * 8;
    pack_all<<<nblk, 256, 0, stream>>>(
        AN, ASs, AO, SFAN, SFAS, SFAO, A4c, A6c, A8d, SaT, M,
        BN, BS, BO, SFBN, SFBS, SFBO, B4c, B6c, B8d, SbT, N);

    dim3 grid(N / 128, M / 128);
    gemm_mx<<<grid, 256, 0, stream>>>(A4c, B4c, A6c, B6c, A8d, B8d,
                                      SaT, SbT, bias, (float*)d_out, M, N);
}